// Round 10
// baseline (123.538 us; speedup 1.0000x reference)
//
#include <hip/hip_runtime.h>
#include <hip/hip_bf16.h>
#include <hip/hip_fp16.h>
#include <math.h>

// Problem constants
#define Bdim 2
#define Tdim 512
#define Cdim 256
#define Hdim 8
#define Edim 32
#define NTYPES 16
#define TI 8       // i-tile size

typedef float v2f __attribute__((ext_vector_type(2)));

// ---------------------------------------------------------------------------
// Kernel 1: fused edge-tables + qkv GEMM. BK=32 (R7).
// blocks 0..383: qkv GEMM (M=1024,K=256,N=768), 32x64 tile, scatter (B,H,T,E)
// blocks 384..399: ekt/evt = emb[t] @ w_edge_{k,v}
// ---------------------------------------------------------------------------
__global__ __launch_bounds__(256) void pre_kernel(
    const float* __restrict__ A, const float* __restrict__ Bw,
    const float* __restrict__ emb, const float* __restrict__ wk,
    const float* __restrict__ wv,
    float* __restrict__ qT, float* __restrict__ kT, float* __restrict__ vT,
    float* __restrict__ ekt, float* __restrict__ evt)
{
    __shared__ float smem[32 * 34 + 32 * 64];   // 12.5 KB
    int tid = threadIdx.x;

    if (blockIdx.x >= 384) {
        // ---- edge tables ----
        int t = blockIdx.x - 384;
        float* se = smem;
        se[tid] = emb[t * Cdim + tid];
        __syncthreads();
        float a = 0.f, b = 0.f;
        for (int k = 0; k < Cdim; ++k) {
            float ev = se[k];
            a = fmaf(ev, wk[k * Cdim + tid], a);
            b = fmaf(ev, wv[k * Cdim + tid], b);
        }
        ekt[t * Cdim + tid] = a;
        evt[t * Cdim + tid] = b;
        return;
    }

    const int N = 3 * Cdim;
    const int K = Cdim;
    float (*As)[34] = (float(*)[34])smem;            // [32][34] transposed A
    float (*Bs)[64] = (float(*)[64])(smem + 32 * 34);// [32][64]
    int m0 = (blockIdx.x / 12) * 32;
    int n0 = (blockIdx.x % 12) * 64;
    int tr = tid >> 4, tc = tid & 15;
    float acc[2][4] = {};

    for (int k0 = 0; k0 < K; k0 += 32) {
        {   // A tile: 32 rows x 32 k, one float4/thread, transposed store
            int r = tid >> 3, kq = (tid & 7) * 4;
            float4 av = *(const float4*)(A + (size_t)(m0 + r) * K + k0 + kq);
            As[kq + 0][r] = av.x;
            As[kq + 1][r] = av.y;
            As[kq + 2][r] = av.z;
            As[kq + 3][r] = av.w;
        }
        {   // B tile: 32 k-rows x 64 n, two float4/thread
            int br = tid >> 4, bc = (tid & 15) * 4;
            *(float4*)&Bs[br][bc] =
                *(const float4*)(Bw + (size_t)(k0 + br) * N + n0 + bc);
            *(float4*)&Bs[br + 16][bc] =
                *(const float4*)(Bw + (size_t)(k0 + br + 16) * N + n0 + bc);
        }
        __syncthreads();
#pragma unroll
        for (int kk = 0; kk < 32; ++kk) {
            float2 a2 = *(float2*)&As[kk][tr * 2];
            float4 b4 = *(float4*)&Bs[kk][tc * 4];
            acc[0][0] = fmaf(a2.x, b4.x, acc[0][0]);
            acc[0][1] = fmaf(a2.x, b4.y, acc[0][1]);
            acc[0][2] = fmaf(a2.x, b4.z, acc[0][2]);
            acc[0][3] = fmaf(a2.x, b4.w, acc[0][3]);
            acc[1][0] = fmaf(a2.y, b4.x, acc[1][0]);
            acc[1][1] = fmaf(a2.y, b4.y, acc[1][1]);
            acc[1][2] = fmaf(a2.y, b4.z, acc[1][2]);
            acc[1][3] = fmaf(a2.y, b4.w, acc[1][3]);
        }
        __syncthreads();
    }
    int sec = n0 >> 8;
    float* dst = (sec == 0) ? qT : (sec == 1) ? kT : vT;
    int cc0 = (n0 & 255) + tc * 4;
    int h = cc0 >> 5;
    int e0 = cc0 & 31;
#pragma unroll
    for (int i = 0; i < 2; ++i) {
        int m = m0 + tr * 2 + i;
        int bq = m >> 9, t = m & (Tdim - 1);
        float4 val = make_float4(acc[i][0], acc[i][1], acc[i][2], acc[i][3]);
        *(float4*)&dst[(((size_t)bq * Hdim + h) * Tdim + t) * Edim + e0] = val;
    }
}

// Quad (4-lane) butterfly sum via DPP quad_perm — pure VALU, no LDS pipe.
__device__ __forceinline__ float quad_reduce_add(float s) {
    int t = __builtin_amdgcn_update_dpp(0, __float_as_int(s), 0xB1, 0xF, 0xF, true); // xor1
    s += __int_as_float(t);
    t = __builtin_amdgcn_update_dpp(0, __float_as_int(s), 0x4E, 0xF, 0xF, true);     // xor2
    s += __int_as_float(t);
    return s;
}

// ---------------------------------------------------------------------------
// Kernel 2: attention. Round-18 (3rd submit; R8/R9 were broker acquisition
// failures, source never ran). CRITICAL-PATH TRIM + PACKED PASS B.
// (1) softmax clipped to chunks 0..(i>>6): 2 passes with biased-score
//     write-back to ss (no tb[] -> no dynamic-index scratch, rule #20).
//     Saves ~5/8 chunks of global bm gather + exp BETWEEN bar2/bar3.
// (2) pass B in packed float2 (ext_vector): acc += (pp*e01)*v01 emits
//     v_pk_mul_f32/v_pk_fma_f32 (full-rate CDNA packed) -> 8->4 VALU/(ii,j).
// fp16 qm pass A (R17), prefetch rotations (R16), no kv staging (R15) kept.
// WATCH: VGPR<=64 keeps 4 blocks/CU (LDS 31.2KB). absmax stays ~2.4e-4.
// Do NOT: min-waves>4 (R12 spill), per-lane-row global k (R14 scatter), kv
// LDS staging (R13), kv dbuf (R11), online softmax (R7-R9), qm removal (R10).
// ---------------------------------------------------------------------------
__global__ __launch_bounds__(512, 4) void attn_kernel(
    const float* __restrict__ qT, const float* __restrict__ kT,
    const float* __restrict__ vT, const int* __restrict__ bm,
    const float* __restrict__ ekt, const float* __restrict__ evt,
    const float* __restrict__ abt, float* __restrict__ y)
{
    __shared__ __half qm[TI][NTYPES][40];        // q*ekt fp16, 80B rows (10.2K)
    __shared__ float ss[TI][516];                // scores -> probs (16.1K)
    __shared__ unsigned int st1pf[Tdim];         // nibbles of bm[b,j,i0+ii] (2K)
    __shared__ float sevt[NTYPES][36];           // (2.25K)
    __shared__ float sabt[NTYPES];
    __shared__ float sinv[TI];
    // total ~31.2 KB -> 4 blocks/CU at VGPR<=64

    float* spart = (float*)ss;                   // overlay AFTER pass B done

    // global LPT order: heaviest tau (njt=4) blocks dispatch first
    const int tau = 63 - (blockIdx.x >> 4);
    const int bh = blockIdx.x & 15;
    const int h = bh & (Hdim - 1);
    const int b = bh >> 3;
    const int tid = threadIdx.x;
    const int wave = tid >> 6;
    const int lane = tid & 63;
    const float inv_scale = 0.17677669529663687f;  // 1/sqrt(32)

    const float* qbase = qT + (size_t)bh * Tdim * Edim;
    const float* kbase = kT + (size_t)bh * Tdim * Edim;
    const float* vbase = vT + (size_t)bh * Tdim * Edim;
    const int* bmb = bm + (size_t)b * Tdim * Tdim;

    const int i0 = tau * TI;
    const int imax = i0 + TI - 1;
    const int jmax = (((imax >> 7) + 1) << 7);

    if (tid < 128) {
        int t = tid >> 3, eq = tid & 7;
        *(float4*)&sevt[t][eq * 4] = *(const float4*)&evt[t * Cdim + h * Edim + eq * 4];
    }
    if (tid < NTYPES) sabt[tid] = abt[tid * Hdim + h];
    // stage nibble table st1pf[j]: bm[b, j, i0..i0+7]
    if (tid < jmax) {
        const int* rowp = bmb + (size_t)tid * Tdim + i0;
        int4 lo = *(const int4*)rowp;
        int4 hi = *(const int4*)(rowp + 4);
        st1pf[tid] =
            ((unsigned)(lo.x & 15)) | (((unsigned)(lo.y & 15)) << 4) |
            (((unsigned)(lo.z & 15)) << 8) | (((unsigned)(lo.w & 15)) << 12) |
            (((unsigned)(hi.x & 15)) << 16) | (((unsigned)(hi.y & 15)) << 20) |
            (((unsigned)(hi.z & 15)) << 24) | (((unsigned)(hi.w & 15)) << 28);
    }
    // build qm[ii][t] = fp16(q[i0+ii] * ekt[t]) directly from global
    for (int idx = tid; idx < TI * NTYPES * 8; idx += 512) {
        int eq = idx & 7;
        int t = (idx >> 3) & (NTYPES - 1);
        int r = idx >> 7;
        float4 qv = *(const float4*)&qbase[(size_t)(i0 + r) * Edim + eq * 4];
        float4 ev = *(const float4*)&ekt[t * Cdim + h * Edim + eq * 4];
        union { __half2 h[2]; uint2 u; } pk;
        pk.h[0] = __floats2half2_rn(qv.x * ev.x, qv.y * ev.y);
        pk.h[1] = __floats2half2_rn(qv.z * ev.z, qv.w * ev.w);
        *(uint2*)&qm[r][t][eq * 4] = pk.u;   // 8B store, 8B-aligned
    }
    __syncthreads();   // [bar 1] qm + st1pf + sevt + sabt ready

    // ---- Pass A: coalesced global k + prefetch rotation + fp16 dot ---------
    {
        const int g = lane >> 2;     // j sub-index within wave's 16-row strip
        const int c = lane & 3;      // e-slice: elements c*8 .. c*8+7
        const int e0 = c << 3;
        int jb = wave << 4;
        if (jb <= imax) {
            const float* krow = kbase + ((size_t)(jb + g) << 5) + e0;
            float4 k0 = *(const float4*)(krow);
            float4 k1 = *(const float4*)(krow + 4);
            unsigned tp = st1pf[jb + g];
            for (;;) {
                const int jbn = jb + 128;
                const bool more = (jbn <= imax);   // wave-uniform
                float4 kn0, kn1;
                unsigned tpn;
                if (more) {                         // prefetch next strip
                    const float* krn = kbase + ((size_t)(jbn + g) << 5) + e0;
                    kn0 = *(const float4*)(krn);
                    kn1 = *(const float4*)(krn + 4);
                    tpn = st1pf[jbn + g];
                }
                const int j = jb + g;
                // convert k slice to packed fp16 once per strip
                __half2 kh0 = __floats2half2_rn(k0.x, k0.y);
                __half2 kh1 = __floats2half2_rn(k0.z, k0.w);
                __half2 kh2 = __floats2half2_rn(k1.x, k1.y);
                __half2 kh3 = __floats2half2_rn(k1.z, k1.w);
                float my0 = 0.f, my1 = 0.f;
#pragma unroll
                for (int ii = 0; ii < 8; ++ii) {
                    int t1 = (tp >> (ii * 4)) & 15;
                    uint4 qw = *(const uint4*)&qm[ii][t1][e0];  // 1x b128
                    __half2 q0 = *(__half2*)&qw.x;
                    __half2 q1 = *(__half2*)&qw.y;
                    __half2 q2 = *(__half2*)&qw.z;
                    __half2 q3 = *(__half2*)&qw.w;
                    __half2 sh = __hmul2(q0, kh0);
                    sh = __hfma2(q1, kh1, sh);
                    sh = __hfma2(q2, kh2, sh);
                    sh = __hfma2(q3, kh3, sh);
                    float s = __low2float(sh) + __high2float(sh);
                    s = quad_reduce_add(s);          // all 4 lanes hold full dot
                    if (ii < 4) my0 = (c == ii) ? s : my0;       // static select
                    else        my1 = (c == (ii - 4)) ? s : my1;
                }
                if (j <= i0 + c)     ss[c][j]     = my0 * inv_scale;
                if (j <= i0 + c + 4) ss[c + 4][j] = my1 * inv_scale;
                if (!more) break;
                k0 = kn0; k1 = kn1; tp = tpn; jb = jbn;
            }
        }
    }
    __syncthreads();   // [bar 2] all scores written

    // Pass-B chunk-0 loads issued EARLY (hide under softmax + [bar 3]).
    const int gid8 = tid >> 3;       // 64 groups of 8 (8 lanes share a j)
    const int eqg4 = (tid & 7) << 2;
    float4 v4c = *(const float4*)&vbase[((size_t)gid8 << 5) + eqg4];
    unsigned tpc = st1pf[gid8];

    // --- softmax, clipped to active chunks (bias from global bm; deferred
    //     normalization). Pass 1 writes the BIASED score back to ss; pass 2
    //     re-reads it — avoids a per-chunk register array (rule #20).
    {
        int ii = wave;
        int i = i0 + ii;
        const int cmax = i >> 6;                    // wave-uniform chunk bound
        const int* brow = bmb + (size_t)i * Tdim;   // bm[b, i, :], coalesced
        float m = -1e30f;
        for (int c = 0; c <= cmax; ++c) {
            int j = (c << 6) + lane;
            float val = ss[ii][j] + sabt[brow[j] & 15];
            if (j <= i) { ss[ii][j] = val; m = fmaxf(m, val); }
        }
        for (int off = 32; off; off >>= 1) m = fmaxf(m, __shfl_xor(m, off));
        float sum = 0.f;
        for (int c = 0; c <= cmax; ++c) {
            int j = (c << 6) + lane;
            float p = __expf(ss[ii][j] - m);
            p = (j <= i) ? p : 0.f;                 // kill idle-lane exp
            sum += p;
            if (j <= i) ss[ii][j] = p;
        }
        for (int off = 32; off; off >>= 1) sum += __shfl_xor(sum, off);
        if (lane == 0) sinv[ii] = 1.0f / sum;
    }
    __syncthreads();   // [bar 3] probs + sinv visible

    // ---- Pass B: PV. Global-direct v + prefetch rotation, PACKED float2 ----
    v2f acc[TI][2];
#pragma unroll
    for (int ii = 0; ii < TI; ++ii) { acc[ii][0] = (v2f)0.f; acc[ii][1] = (v2f)0.f; }
    for (int jc = 0;; ++jc) {
        const bool more = ((jc + 1) << 6) <= imax;   // block-uniform
        float4 v4n;
        unsigned tpn;
        if (more) {                                   // prefetch next chunk
            const int jn = ((jc + 1) << 6) + gid8;
            v4n = *(const float4*)&vbase[((size_t)jn << 5) + eqg4];
            tpn = st1pf[jn];
        }
        const int j = (jc << 6) + gid8;
        const v2f v01 = {v4c.x, v4c.y};
        const v2f v23 = {v4c.z, v4c.w};
#pragma unroll
        for (int ii = 0; ii < TI; ++ii) {
            const int i = i0 + ii;
            if ((jc << 6) > i) continue;        // block-uniform skip
            float p = (j <= i) ? ss[ii][j] : 0.f;
            int t1 = (tpc >> (ii * 4)) & 15;
            const v2f e01 = *(const v2f*)&sevt[t1][eqg4];
            const v2f e23 = *(const v2f*)&sevt[t1][eqg4 + 2];
            v2f pp = {p, p};
            acc[ii][0] += (pp * e01) * v01;     // v_pk_mul + v_pk_fma
            acc[ii][1] += (pp * e23) * v23;
        }
        if (!more) break;
        v4c = v4n; tpc = tpn;
    }
    __syncthreads();   // [bar 4] all ss reads done -> spart may overlay
    // reduce across the wave's 8 groups (lane bits 3,4,5)
#pragma unroll
    for (int ii = 0; ii < TI; ++ii) {
#pragma unroll
        for (int m = 8; m <= 32; m <<= 1) {
            acc[ii][0][0] += __shfl_xor(acc[ii][0][0], m);
            acc[ii][0][1] += __shfl_xor(acc[ii][0][1], m);
            acc[ii][1][0] += __shfl_xor(acc[ii][1][0], m);
            acc[ii][1][1] += __shfl_xor(acc[ii][1][1], m);
        }
    }
    if (lane < 8) {
#pragma unroll
        for (int ii = 0; ii < TI; ++ii) {
            float4 av = make_float4(acc[ii][0][0], acc[ii][0][1],
                                    acc[ii][1][0], acc[ii][1][1]);
            *(float4*)&spart[((wave * TI + ii) << 5) + lane * 4] = av;
        }
    }
    __syncthreads();   // [bar 5]
    if (tid < TI * Edim) {
        int ii = tid >> 5, e = tid & 31;
        float yv = 0.f;
#pragma unroll
        for (int w = 0; w < 8; ++w) yv += spart[((w * TI + ii) << 5) + e];
        yv *= sinv[ii];
        y[((size_t)(b * Tdim + i0 + ii)) * Cdim + h * Edim + e] = yv;
    }
}

// ---------------------------------------------------------------------------
// Kernel 3: proj GEMM (M=1024, K=256, N=256) -> d_out (B,T,C).
// 32x32 tiles, 256 blocks.
// ---------------------------------------------------------------------------
__global__ __launch_bounds__(256) void proj_gemm_kernel(
    const float* __restrict__ A, const float* __restrict__ Bw,
    float* __restrict__ out)
{
    const int N = Cdim;
    const int K = Cdim;
    __shared__ float As[16][34];
    __shared__ float Bs[16][36];
    int m0 = blockIdx.y * 32;
    int n0 = blockIdx.x * 32;
    int tid = threadIdx.x;
    int tr = tid >> 3;          // 0..31 (row)
    int tc = tid & 7;           // 0..7  (col quad)
    float acc[4] = {};

    for (int k0 = 0; k0 < K; k0 += 16) {
        if (tid < 128) {
            int r = tid >> 2, kq = (tid & 3) * 4;
            float4 av = *(const float4*)(A + (size_t)(m0 + r) * K + k0 + kq);
            As[kq + 0][r] = av.x;
            As[kq + 1][r] = av.y;
            As[kq + 2][r] = av.z;
            As[kq + 3][r] = av.w;
        } else {
            int t2 = tid - 128;
            int r = t2 >> 3, c = (t2 & 7) * 4;   // 16 rows x 32 cols
            *(float4*)&Bs[r][c] =
                *(const float4*)(Bw + (size_t)(k0 + r) * N + n0 + c);
        }
        __syncthreads();
#pragma unroll
        for (int kk = 0; kk < 16; ++kk) {
            float a = As[kk][tr];
            float4 b4 = *(float4*)&Bs[kk][tc * 4];
            acc[0] = fmaf(a, b4.x, acc[0]);
            acc[1] = fmaf(a, b4.y, acc[1]);
            acc[2] = fmaf(a, b4.z, acc[2]);
            acc[3] = fmaf(a, b4.w, acc[3]);
        }
        __syncthreads();
    }
    float4 val = make_float4(acc[0], acc[1], acc[2], acc[3]);
    *(float4*)&out[(size_t)(m0 + tr) * N + n0 + tc * 4] = val;
}

// ---------------------------------------------------------------------------
extern "C" void kernel_launch(void* const* d_in, const int* in_sizes, int n_in,
                              void* d_out, int out_size, void* d_ws, size_t ws_size,
                              hipStream_t stream) {
    (void)in_sizes; (void)n_in; (void)out_size; (void)ws_size;
    const float* x = (const float*)d_in[0];
    const int* bias_matrix = (const int*)d_in[1];
    const float* w_attn = (const float*)d_in[2];
    const float* w_proj = (const float*)d_in[3];
    const float* w_edge_k = (const float*)d_in[4];
    const float* w_edge_v = (const float*)d_in[5];
    const float* edge_emb = (const float*)d_in[6];
    const float* attn_bias = (const float*)d_in[7];
    float* out = (float*)d_out;

    const size_t n_qkv = (size_t)Bdim * Hdim * Tdim * Edim;
    float* ws = (float*)d_ws;
    float* qT = ws;
    float* kT = qT + n_qkv;
    float* vT = kT + n_qkv;
    float* y = vT + n_qkv;
    float* ekt = y + (size_t)Bdim * Tdim * Cdim;
    float* evt = ekt + (size_t)NTYPES * Cdim;

    pre_kernel<<<400, 256, 0, stream>>>(x, w_attn, edge_emb, w_edge_k, w_edge_v,
                                        qT, kT, vT, ekt, evt);
    attn_kernel<<<dim3(64 * 16), 512, 0, stream>>>(qT, kT, vT, bias_matrix,
                                                   ekt, evt, attn_bias, y);
    proj_gemm_kernel<<<dim3(8, 32), 256, 0, stream>>>(y, w_proj, out);
}

// Round 11
// 121.832 us; speedup vs baseline: 1.0140x; 1.0140x over previous
//
#include <hip/hip_runtime.h>
#include <hip/hip_bf16.h>
#include <hip/hip_fp16.h>
#include <math.h>

// Problem constants
#define Bdim 2
#define Tdim 512
#define Cdim 256
#define Hdim 8
#define Edim 32
#define NTYPES 16
#define TI 8       // i-tile size

typedef float v2f __attribute__((ext_vector_type(2)));

// ---------------------------------------------------------------------------
// Kernel 1: fused edge-tables + qkv GEMM. BK=32 (R7).
// blocks 0..383: qkv GEMM (M=1024,K=256,N=768), 32x64 tile, scatter (B,H,T,E)
// blocks 384..399: ekt/evt = emb[t] @ w_edge_{k,v}
// ---------------------------------------------------------------------------
__global__ __launch_bounds__(256) void pre_kernel(
    const float* __restrict__ A, const float* __restrict__ Bw,
    const float* __restrict__ emb, const float* __restrict__ wk,
    const float* __restrict__ wv,
    float* __restrict__ qT, float* __restrict__ kT, float* __restrict__ vT,
    float* __restrict__ ekt, float* __restrict__ evt)
{
    __shared__ float smem[32 * 34 + 32 * 64];   // 12.5 KB
    int tid = threadIdx.x;

    if (blockIdx.x >= 384) {
        // ---- edge tables ----
        int t = blockIdx.x - 384;
        float* se = smem;
        se[tid] = emb[t * Cdim + tid];
        __syncthreads();
        float a = 0.f, b = 0.f;
        for (int k = 0; k < Cdim; ++k) {
            float ev = se[k];
            a = fmaf(ev, wk[k * Cdim + tid], a);
            b = fmaf(ev, wv[k * Cdim + tid], b);
        }
        ekt[t * Cdim + tid] = a;
        evt[t * Cdim + tid] = b;
        return;
    }

    const int N = 3 * Cdim;
    const int K = Cdim;
    float (*As)[34] = (float(*)[34])smem;            // [32][34] transposed A
    float (*Bs)[64] = (float(*)[64])(smem + 32 * 34);// [32][64]
    int m0 = (blockIdx.x / 12) * 32;
    int n0 = (blockIdx.x % 12) * 64;
    int tr = tid >> 4, tc = tid & 15;
    float acc[2][4] = {};

    for (int k0 = 0; k0 < K; k0 += 32) {
        {   // A tile: 32 rows x 32 k, one float4/thread, transposed store
            int r = tid >> 3, kq = (tid & 7) * 4;
            float4 av = *(const float4*)(A + (size_t)(m0 + r) * K + k0 + kq);
            As[kq + 0][r] = av.x;
            As[kq + 1][r] = av.y;
            As[kq + 2][r] = av.z;
            As[kq + 3][r] = av.w;
        }
        {   // B tile: 32 k-rows x 64 n, two float4/thread
            int br = tid >> 4, bc = (tid & 15) * 4;
            *(float4*)&Bs[br][bc] =
                *(const float4*)(Bw + (size_t)(k0 + br) * N + n0 + bc);
            *(float4*)&Bs[br + 16][bc] =
                *(const float4*)(Bw + (size_t)(k0 + br + 16) * N + n0 + bc);
        }
        __syncthreads();
#pragma unroll
        for (int kk = 0; kk < 32; ++kk) {
            float2 a2 = *(float2*)&As[kk][tr * 2];
            float4 b4 = *(float4*)&Bs[kk][tc * 4];
            acc[0][0] = fmaf(a2.x, b4.x, acc[0][0]);
            acc[0][1] = fmaf(a2.x, b4.y, acc[0][1]);
            acc[0][2] = fmaf(a2.x, b4.z, acc[0][2]);
            acc[0][3] = fmaf(a2.x, b4.w, acc[0][3]);
            acc[1][0] = fmaf(a2.y, b4.x, acc[1][0]);
            acc[1][1] = fmaf(a2.y, b4.y, acc[1][1]);
            acc[1][2] = fmaf(a2.y, b4.z, acc[1][2]);
            acc[1][3] = fmaf(a2.y, b4.w, acc[1][3]);
        }
        __syncthreads();
    }
    int sec = n0 >> 8;
    float* dst = (sec == 0) ? qT : (sec == 1) ? kT : vT;
    int cc0 = (n0 & 255) + tc * 4;
    int h = cc0 >> 5;
    int e0 = cc0 & 31;
#pragma unroll
    for (int i = 0; i < 2; ++i) {
        int m = m0 + tr * 2 + i;
        int bq = m >> 9, t = m & (Tdim - 1);
        float4 val = make_float4(acc[i][0], acc[i][1], acc[i][2], acc[i][3]);
        *(float4*)&dst[(((size_t)bq * Hdim + h) * Tdim + t) * Edim + e0] = val;
    }
}

// Quad (4-lane) butterfly sum via DPP quad_perm — pure VALU, no LDS pipe.
__device__ __forceinline__ float quad_reduce_add(float s) {
    int t = __builtin_amdgcn_update_dpp(0, __float_as_int(s), 0xB1, 0xF, 0xF, true); // xor1
    s += __int_as_float(t);
    t = __builtin_amdgcn_update_dpp(0, __float_as_int(s), 0x4E, 0xF, 0xF, true);     // xor2
    s += __int_as_float(t);
    return s;
}

// ---------------------------------------------------------------------------
// Kernel 2: attention. Round-19: BIAS FUSED INTO PASS A.
// R18 post-mortem (123.5 vs R7 121.3): clipped softmax + packed pass B were
// within harness noise (fills vary +-2us/window) -> critical-path work was
// hiding under latency. This round removes softmax's remaining GLOBAL
// traffic: st2pf re-added (2K LDS; bm[b,i0+ii,j] nibbles, built in prologue
// under qm-build latency), bias added at pass-A score write (same fp32 add
// order -> absmax bit-identical). Softmax pass-1 is now a pure LDS max scan
// (no bm gather, no ss write-back); bm untouched after prologue.
// LDS 33.2KB -> still 4 blocks/CU IF VGPR<=64 (watch; 65-85 -> 3 blocks).
// Do NOT: min-waves>4 (R12 spill), per-lane-row global k (R14 scatter), kv
// LDS staging (R13), kv dbuf (R11), online softmax (R7-R9), qm removal (R10).
// ---------------------------------------------------------------------------
__global__ __launch_bounds__(512, 4) void attn_kernel(
    const float* __restrict__ qT, const float* __restrict__ kT,
    const float* __restrict__ vT, const int* __restrict__ bm,
    const float* __restrict__ ekt, const float* __restrict__ evt,
    const float* __restrict__ abt, float* __restrict__ y)
{
    __shared__ __half qm[TI][NTYPES][40];        // q*ekt fp16, 80B rows (10.2K)
    __shared__ float ss[TI][516];                // scores -> probs (16.1K)
    __shared__ unsigned int st1pf[Tdim];         // nibbles of bm[b,j,i0+ii] (2K)
    __shared__ unsigned int st2pf[Tdim];         // nibbles of bm[b,i0+ii,j] (2K)
    __shared__ float sevt[NTYPES][36];           // (2.25K)
    __shared__ float sabt[NTYPES];
    __shared__ float sinv[TI];
    // total ~33.2 KB -> 4 blocks/CU at VGPR<=64

    float* spart = (float*)ss;                   // overlay AFTER pass B done

    // global LPT order: heaviest tau (njt=4) blocks dispatch first
    const int tau = 63 - (blockIdx.x >> 4);
    const int bh = blockIdx.x & 15;
    const int h = bh & (Hdim - 1);
    const int b = bh >> 3;
    const int tid = threadIdx.x;
    const int wave = tid >> 6;
    const int lane = tid & 63;
    const float inv_scale = 0.17677669529663687f;  // 1/sqrt(32)

    const float* qbase = qT + (size_t)bh * Tdim * Edim;
    const float* kbase = kT + (size_t)bh * Tdim * Edim;
    const float* vbase = vT + (size_t)bh * Tdim * Edim;
    const int* bmb = bm + (size_t)b * Tdim * Tdim;

    const int i0 = tau * TI;
    const int imax = i0 + TI - 1;
    const int jmax = (((imax >> 7) + 1) << 7);

    if (tid < 128) {
        int t = tid >> 3, eq = tid & 7;
        *(float4*)&sevt[t][eq * 4] = *(const float4*)&evt[t * Cdim + h * Edim + eq * 4];
    }
    if (tid < NTYPES) sabt[tid] = abt[tid * Hdim + h];
    // stage nibble tables for the whole block
    if (tid < jmax) {
        // st1pf[j]: bm[b, j, i0..i0+7]  (score/PV modulation types)
        const int* rowp = bmb + (size_t)tid * Tdim + i0;
        int4 lo = *(const int4*)rowp;
        int4 hi = *(const int4*)(rowp + 4);
        st1pf[tid] =
            ((unsigned)(lo.x & 15)) | (((unsigned)(lo.y & 15)) << 4) |
            (((unsigned)(lo.z & 15)) << 8) | (((unsigned)(lo.w & 15)) << 12) |
            (((unsigned)(hi.x & 15)) << 16) | (((unsigned)(hi.y & 15)) << 20) |
            (((unsigned)(hi.z & 15)) << 24) | (((unsigned)(hi.w & 15)) << 28);
        // st2pf[j]: bm[b, i0+ii, j]  (attn-bias types; coalesced across tid)
        unsigned w2 = 0;
#pragma unroll
        for (int iiq = 0; iiq < 8; ++iiq)
            w2 |= ((unsigned)(bmb[(size_t)(i0 + iiq) * Tdim + tid] & 15)) << (iiq * 4);
        st2pf[tid] = w2;
    }
    // build qm[ii][t] = fp16(q[i0+ii] * ekt[t]) directly from global
    for (int idx = tid; idx < TI * NTYPES * 8; idx += 512) {
        int eq = idx & 7;
        int t = (idx >> 3) & (NTYPES - 1);
        int r = idx >> 7;
        float4 qv = *(const float4*)&qbase[(size_t)(i0 + r) * Edim + eq * 4];
        float4 ev = *(const float4*)&ekt[t * Cdim + h * Edim + eq * 4];
        union { __half2 h[2]; uint2 u; } pk;
        pk.h[0] = __floats2half2_rn(qv.x * ev.x, qv.y * ev.y);
        pk.h[1] = __floats2half2_rn(qv.z * ev.z, qv.w * ev.w);
        *(uint2*)&qm[r][t][eq * 4] = pk.u;   // 8B store, 8B-aligned
    }
    __syncthreads();   // [bar 1] qm + tables ready

    // ---- Pass A: coalesced global k + prefetch rotation + fp16 dot;
    //      attn-bias added at score write (st2pf) ----
    {
        const int g = lane >> 2;     // j sub-index within wave's 16-row strip
        const int c = lane & 3;      // e-slice: elements c*8 .. c*8+7
        const int e0 = c << 3;
        int jb = wave << 4;
        if (jb <= imax) {
            const float* krow = kbase + ((size_t)(jb + g) << 5) + e0;
            float4 k0 = *(const float4*)(krow);
            float4 k1 = *(const float4*)(krow + 4);
            unsigned tp = st1pf[jb + g];
            unsigned tp2 = st2pf[jb + g];
            for (;;) {
                const int jbn = jb + 128;
                const bool more = (jbn <= imax);   // wave-uniform
                float4 kn0, kn1;
                unsigned tpn, tpn2;
                if (more) {                         // prefetch next strip
                    const float* krn = kbase + ((size_t)(jbn + g) << 5) + e0;
                    kn0 = *(const float4*)(krn);
                    kn1 = *(const float4*)(krn + 4);
                    tpn = st1pf[jbn + g];
                    tpn2 = st2pf[jbn + g];
                }
                const int j = jb + g;
                // convert k slice to packed fp16 once per strip
                __half2 kh0 = __floats2half2_rn(k0.x, k0.y);
                __half2 kh1 = __floats2half2_rn(k0.z, k0.w);
                __half2 kh2 = __floats2half2_rn(k1.x, k1.y);
                __half2 kh3 = __floats2half2_rn(k1.z, k1.w);
                float my0 = 0.f, my1 = 0.f;
#pragma unroll
                for (int ii = 0; ii < 8; ++ii) {
                    int t1 = (tp >> (ii * 4)) & 15;
                    uint4 qw = *(const uint4*)&qm[ii][t1][e0];  // 1x b128
                    __half2 q0 = *(__half2*)&qw.x;
                    __half2 q1 = *(__half2*)&qw.y;
                    __half2 q2 = *(__half2*)&qw.z;
                    __half2 q3 = *(__half2*)&qw.w;
                    __half2 sh = __hmul2(q0, kh0);
                    sh = __hfma2(q1, kh1, sh);
                    sh = __hfma2(q2, kh2, sh);
                    sh = __hfma2(q3, kh3, sh);
                    float s = __low2float(sh) + __high2float(sh);
                    s = quad_reduce_add(s);          // all 4 lanes hold full dot
                    if (ii < 4) my0 = (c == ii) ? s : my0;       // static select
                    else        my1 = (c == (ii - 4)) ? s : my1;
                }
                if (j <= i0 + c)
                    ss[c][j] = my0 * inv_scale + sabt[(tp2 >> (c * 4)) & 15];
                if (j <= i0 + c + 4)
                    ss[c + 4][j] = my1 * inv_scale + sabt[(tp2 >> ((c + 4) * 4)) & 15];
                if (!more) break;
                k0 = kn0; k1 = kn1; tp = tpn; tp2 = tpn2; jb = jbn;
            }
        }
    }
    __syncthreads();   // [bar 2] all (biased) scores written

    // Pass-B chunk-0 loads issued EARLY (hide under softmax + [bar 3]).
    const int gid8 = tid >> 3;       // 64 groups of 8 (8 lanes share a j)
    const int eqg4 = (tid & 7) << 2;
    float4 v4c = *(const float4*)&vbase[((size_t)gid8 << 5) + eqg4];
    unsigned tpc = st1pf[gid8];

    // --- softmax over active chunks: pure LDS max scan, then exp+sum.
    //     Bias already in ss (pass A) -> no global bm traffic here.
    {
        int ii = wave;
        int i = i0 + ii;
        const int cmax = i >> 6;                    // wave-uniform chunk bound
        float m = -1e30f;
        for (int c = 0; c <= cmax; ++c) {
            int j = (c << 6) + lane;
            float val = ss[ii][j];                  // garbage if j>i, masked next
            m = fmaxf(m, (j <= i) ? val : -1e30f);
        }
        for (int off = 32; off; off >>= 1) m = fmaxf(m, __shfl_xor(m, off));
        float sum = 0.f;
        for (int c = 0; c <= cmax; ++c) {
            int j = (c << 6) + lane;
            float p = __expf(ss[ii][j] - m);
            p = (j <= i) ? p : 0.f;                 // kill idle-lane exp
            sum += p;
            if (j <= i) ss[ii][j] = p;
        }
        for (int off = 32; off; off >>= 1) sum += __shfl_xor(sum, off);
        if (lane == 0) sinv[ii] = 1.0f / sum;
    }
    __syncthreads();   // [bar 3] probs + sinv visible

    // ---- Pass B: PV. Global-direct v + prefetch rotation, PACKED float2 ----
    v2f acc[TI][2];
#pragma unroll
    for (int ii = 0; ii < TI; ++ii) { acc[ii][0] = (v2f)0.f; acc[ii][1] = (v2f)0.f; }
    for (int jc = 0;; ++jc) {
        const bool more = ((jc + 1) << 6) <= imax;   // block-uniform
        float4 v4n;
        unsigned tpn;
        if (more) {                                   // prefetch next chunk
            const int jn = ((jc + 1) << 6) + gid8;
            v4n = *(const float4*)&vbase[((size_t)jn << 5) + eqg4];
            tpn = st1pf[jn];
        }
        const int j = (jc << 6) + gid8;
        const v2f v01 = {v4c.x, v4c.y};
        const v2f v23 = {v4c.z, v4c.w};
#pragma unroll
        for (int ii = 0; ii < TI; ++ii) {
            const int i = i0 + ii;
            if ((jc << 6) > i) continue;        // block-uniform skip
            float p = (j <= i) ? ss[ii][j] : 0.f;
            int t1 = (tpc >> (ii * 4)) & 15;
            const v2f e01 = *(const v2f*)&sevt[t1][eqg4];
            const v2f e23 = *(const v2f*)&sevt[t1][eqg4 + 2];
            v2f pp = {p, p};
            acc[ii][0] += (pp * e01) * v01;     // v_pk_mul + v_pk_fma
            acc[ii][1] += (pp * e23) * v23;
        }
        if (!more) break;
        v4c = v4n; tpc = tpn;
    }
    __syncthreads();   // [bar 4] all ss reads done -> spart may overlay
    // reduce across the wave's 8 groups (lane bits 3,4,5)
#pragma unroll
    for (int ii = 0; ii < TI; ++ii) {
#pragma unroll
        for (int m = 8; m <= 32; m <<= 1) {
            acc[ii][0][0] += __shfl_xor(acc[ii][0][0], m);
            acc[ii][0][1] += __shfl_xor(acc[ii][0][1], m);
            acc[ii][1][0] += __shfl_xor(acc[ii][1][0], m);
            acc[ii][1][1] += __shfl_xor(acc[ii][1][1], m);
        }
    }
    if (lane < 8) {
#pragma unroll
        for (int ii = 0; ii < TI; ++ii) {
            float4 av = make_float4(acc[ii][0][0], acc[ii][0][1],
                                    acc[ii][1][0], acc[ii][1][1]);
            *(float4*)&spart[((wave * TI + ii) << 5) + lane * 4] = av;
        }
    }
    __syncthreads();   // [bar 5]
    if (tid < TI * Edim) {
        int ii = tid >> 5, e = tid & 31;
        float yv = 0.f;
#pragma unroll
        for (int w = 0; w < 8; ++w) yv += spart[((w * TI + ii) << 5) + e];
        yv *= sinv[ii];
        y[((size_t)(b * Tdim + i0 + ii)) * Cdim + h * Edim + e] = yv;
    }
}

// ---------------------------------------------------------------------------
// Kernel 3: proj GEMM (M=1024, K=256, N=256) -> d_out (B,T,C).
// 32x32 tiles, 256 blocks.
// ---------------------------------------------------------------------------
__global__ __launch_bounds__(256) void proj_gemm_kernel(
    const float* __restrict__ A, const float* __restrict__ Bw,
    float* __restrict__ out)
{
    const int N = Cdim;
    const int K = Cdim;
    __shared__ float As[16][34];
    __shared__ float Bs[16][36];
    int m0 = blockIdx.y * 32;
    int n0 = blockIdx.x * 32;
    int tid = threadIdx.x;
    int tr = tid >> 3;          // 0..31 (row)
    int tc = tid & 7;           // 0..7  (col quad)
    float acc[4] = {};

    for (int k0 = 0; k0 < K; k0 += 16) {
        if (tid < 128) {
            int r = tid >> 2, kq = (tid & 3) * 4;
            float4 av = *(const float4*)(A + (size_t)(m0 + r) * K + k0 + kq);
            As[kq + 0][r] = av.x;
            As[kq + 1][r] = av.y;
            As[kq + 2][r] = av.z;
            As[kq + 3][r] = av.w;
        } else {
            int t2 = tid - 128;
            int r = t2 >> 3, c = (t2 & 7) * 4;   // 16 rows x 32 cols
            *(float4*)&Bs[r][c] =
                *(const float4*)(Bw + (size_t)(k0 + r) * N + n0 + c);
        }
        __syncthreads();
#pragma unroll
        for (int kk = 0; kk < 16; ++kk) {
            float a = As[kk][tr];
            float4 b4 = *(float4*)&Bs[kk][tc * 4];
            acc[0] = fmaf(a, b4.x, acc[0]);
            acc[1] = fmaf(a, b4.y, acc[1]);
            acc[2] = fmaf(a, b4.z, acc[2]);
            acc[3] = fmaf(a, b4.w, acc[3]);
        }
        __syncthreads();
    }
    float4 val = make_float4(acc[0], acc[1], acc[2], acc[3]);
    *(float4*)&out[(size_t)(m0 + tr) * N + n0 + tc * 4] = val;
}

// ---------------------------------------------------------------------------
extern "C" void kernel_launch(void* const* d_in, const int* in_sizes, int n_in,
                              void* d_out, int out_size, void* d_ws, size_t ws_size,
                              hipStream_t stream) {
    (void)in_sizes; (void)n_in; (void)out_size; (void)ws_size;
    const float* x = (const float*)d_in[0];
    const int* bias_matrix = (const int*)d_in[1];
    const float* w_attn = (const float*)d_in[2];
    const float* w_proj = (const float*)d_in[3];
    const float* w_edge_k = (const float*)d_in[4];
    const float* w_edge_v = (const float*)d_in[5];
    const float* edge_emb = (const float*)d_in[6];
    const float* attn_bias = (const float*)d_in[7];
    float* out = (float*)d_out;

    const size_t n_qkv = (size_t)Bdim * Hdim * Tdim * Edim;
    float* ws = (float*)d_ws;
    float* qT = ws;
    float* kT = qT + n_qkv;
    float* vT = kT + n_qkv;
    float* y = vT + n_qkv;
    float* ekt = y + (size_t)Bdim * Tdim * Cdim;
    float* evt = ekt + (size_t)NTYPES * Cdim;

    pre_kernel<<<400, 256, 0, stream>>>(x, w_attn, edge_emb, w_edge_k, w_edge_v,
                                        qT, kT, vT, ekt, evt);
    attn_kernel<<<dim3(64 * 16), 512, 0, stream>>>(qT, kT, vT, bias_matrix,
                                                   ekt, evt, attn_bias, y);
    proj_gemm_kernel<<<dim3(8, 32), 256, 0, stream>>>(y, w_proj, out);
}

// Round 12
// 121.646 us; speedup vs baseline: 1.0156x; 1.0015x over previous
//
#include <hip/hip_runtime.h>
#include <hip/hip_bf16.h>
#include <hip/hip_fp16.h>
#include <math.h>

// Problem constants
#define Bdim 2
#define Tdim 512
#define Cdim 256
#define Hdim 8
#define Edim 32
#define NTYPES 16
#define TI 8       // i-tile size

typedef float v2f __attribute__((ext_vector_type(2)));

// ---------------------------------------------------------------------------
// Kernel 1: fused edge-tables + qkv GEMM. BK=32 (R7).
// blocks 0..383: qkv GEMM (M=1024,K=256,N=768), 32x64 tile, scatter (B,H,T,E)
// blocks 384..399: ekt/evt = emb[t] @ w_edge_{k,v}
// ---------------------------------------------------------------------------
__global__ __launch_bounds__(256) void pre_kernel(
    const float* __restrict__ A, const float* __restrict__ Bw,
    const float* __restrict__ emb, const float* __restrict__ wk,
    const float* __restrict__ wv,
    float* __restrict__ qT, float* __restrict__ kT, float* __restrict__ vT,
    float* __restrict__ ekt, float* __restrict__ evt)
{
    __shared__ float smem[32 * 34 + 32 * 64];   // 12.5 KB
    int tid = threadIdx.x;

    if (blockIdx.x >= 384) {
        // ---- edge tables ----
        int t = blockIdx.x - 384;
        float* se = smem;
        se[tid] = emb[t * Cdim + tid];
        __syncthreads();
        float a = 0.f, b = 0.f;
        for (int k = 0; k < Cdim; ++k) {
            float ev = se[k];
            a = fmaf(ev, wk[k * Cdim + tid], a);
            b = fmaf(ev, wv[k * Cdim + tid], b);
        }
        ekt[t * Cdim + tid] = a;
        evt[t * Cdim + tid] = b;
        return;
    }

    const int N = 3 * Cdim;
    const int K = Cdim;
    float (*As)[34] = (float(*)[34])smem;            // [32][34] transposed A
    float (*Bs)[64] = (float(*)[64])(smem + 32 * 34);// [32][64]
    int m0 = (blockIdx.x / 12) * 32;
    int n0 = (blockIdx.x % 12) * 64;
    int tr = tid >> 4, tc = tid & 15;
    float acc[2][4] = {};

    for (int k0 = 0; k0 < K; k0 += 32) {
        {   // A tile: 32 rows x 32 k, one float4/thread, transposed store
            int r = tid >> 3, kq = (tid & 7) * 4;
            float4 av = *(const float4*)(A + (size_t)(m0 + r) * K + k0 + kq);
            As[kq + 0][r] = av.x;
            As[kq + 1][r] = av.y;
            As[kq + 2][r] = av.z;
            As[kq + 3][r] = av.w;
        }
        {   // B tile: 32 k-rows x 64 n, two float4/thread
            int br = tid >> 4, bc = (tid & 15) * 4;
            *(float4*)&Bs[br][bc] =
                *(const float4*)(Bw + (size_t)(k0 + br) * N + n0 + bc);
            *(float4*)&Bs[br + 16][bc] =
                *(const float4*)(Bw + (size_t)(k0 + br + 16) * N + n0 + bc);
        }
        __syncthreads();
#pragma unroll
        for (int kk = 0; kk < 32; ++kk) {
            float2 a2 = *(float2*)&As[kk][tr * 2];
            float4 b4 = *(float4*)&Bs[kk][tc * 4];
            acc[0][0] = fmaf(a2.x, b4.x, acc[0][0]);
            acc[0][1] = fmaf(a2.x, b4.y, acc[0][1]);
            acc[0][2] = fmaf(a2.x, b4.z, acc[0][2]);
            acc[0][3] = fmaf(a2.x, b4.w, acc[0][3]);
            acc[1][0] = fmaf(a2.y, b4.x, acc[1][0]);
            acc[1][1] = fmaf(a2.y, b4.y, acc[1][1]);
            acc[1][2] = fmaf(a2.y, b4.z, acc[1][2]);
            acc[1][3] = fmaf(a2.y, b4.w, acc[1][3]);
        }
        __syncthreads();
    }
    int sec = n0 >> 8;
    float* dst = (sec == 0) ? qT : (sec == 1) ? kT : vT;
    int cc0 = (n0 & 255) + tc * 4;
    int h = cc0 >> 5;
    int e0 = cc0 & 31;
#pragma unroll
    for (int i = 0; i < 2; ++i) {
        int m = m0 + tr * 2 + i;
        int bq = m >> 9, t = m & (Tdim - 1);
        float4 val = make_float4(acc[i][0], acc[i][1], acc[i][2], acc[i][3]);
        *(float4*)&dst[(((size_t)bq * Hdim + h) * Tdim + t) * Edim + e0] = val;
    }
}

// Quad (4-lane) butterfly sum via DPP quad_perm — pure VALU, no LDS pipe.
__device__ __forceinline__ float quad_reduce_add(float s) {
    int t = __builtin_amdgcn_update_dpp(0, __float_as_int(s), 0xB1, 0xF, 0xF, true); // xor1
    s += __int_as_float(t);
    t = __builtin_amdgcn_update_dpp(0, __float_as_int(s), 0x4E, 0xF, 0xF, true);     // xor2
    s += __int_as_float(t);
    return s;
}

// ---------------------------------------------------------------------------
// Kernel 2: attention. Round-20: PER-CU LOAD-BALANCED TAU PERMUTATION.
// R19 post-mortem: bias-fusion landed within noise (R7 121.3/R18 123.5/R19
// 121.8) — three work-removal rounds absorbed by latency; kernel is not
// issue-bound. Structural term left: grid=1024 = exactly 4 blocks/CU, ALL
// co-resident at launch => no queue, attn time = max over CUs of its 4
// blocks' work. Blocks n and n+256 co-locate under both plausible dispatch
// maps (sequential fill and XCD round-robin). Old tau=63-(bid>>4) gave CU
// group a the taus {63-a,47-a,31-a,15-a}: variable work 156-4a, 96..156
// spread (~40%); worst CU sets duration. New bijective map:
//   g<16: 63-g | g<32: g-16 | g<48: 79-g | else: g-32
// -> co-resident group {a,a+16,a+32,a+48} = taus {63-a, a, 47-a, 16+a},
// variable-work sum 126 CONSTANT. Everything else identical to R19.
// Do NOT: min-waves>4 (R12 spill), per-lane-row global k (R14 scatter), kv
// LDS staging (R13), kv dbuf (R11), online softmax (R7-R9), qm removal (R10).
// ---------------------------------------------------------------------------
__global__ __launch_bounds__(512, 4) void attn_kernel(
    const float* __restrict__ qT, const float* __restrict__ kT,
    const float* __restrict__ vT, const int* __restrict__ bm,
    const float* __restrict__ ekt, const float* __restrict__ evt,
    const float* __restrict__ abt, float* __restrict__ y)
{
    __shared__ __half qm[TI][NTYPES][40];        // q*ekt fp16, 80B rows (10.2K)
    __shared__ float ss[TI][516];                // scores -> probs (16.1K)
    __shared__ unsigned int st1pf[Tdim];         // nibbles of bm[b,j,i0+ii] (2K)
    __shared__ unsigned int st2pf[Tdim];         // nibbles of bm[b,i0+ii,j] (2K)
    __shared__ float sevt[NTYPES][36];           // (2.25K)
    __shared__ float sabt[NTYPES];
    __shared__ float sinv[TI];
    // total ~33.2 KB -> 4 blocks/CU at VGPR<=64

    float* spart = (float*)ss;                   // overlay AFTER pass B done

    // per-CU load-balanced bijective tau map (blocks g,g+16,g+32,g+48
    // co-locate on one CU; their variable work sums to a constant)
    const int grp = blockIdx.x >> 4;
    const int tau = (grp < 16) ? (63 - grp)
                  : (grp < 32) ? (grp - 16)
                  : (grp < 48) ? (79 - grp)
                  : (grp - 32);
    const int bh = blockIdx.x & 15;
    const int h = bh & (Hdim - 1);
    const int b = bh >> 3;
    const int tid = threadIdx.x;
    const int wave = tid >> 6;
    const int lane = tid & 63;
    const float inv_scale = 0.17677669529663687f;  // 1/sqrt(32)

    const float* qbase = qT + (size_t)bh * Tdim * Edim;
    const float* kbase = kT + (size_t)bh * Tdim * Edim;
    const float* vbase = vT + (size_t)bh * Tdim * Edim;
    const int* bmb = bm + (size_t)b * Tdim * Tdim;

    const int i0 = tau * TI;
    const int imax = i0 + TI - 1;
    const int jmax = (((imax >> 7) + 1) << 7);

    if (tid < 128) {
        int t = tid >> 3, eq = tid & 7;
        *(float4*)&sevt[t][eq * 4] = *(const float4*)&evt[t * Cdim + h * Edim + eq * 4];
    }
    if (tid < NTYPES) sabt[tid] = abt[tid * Hdim + h];
    // stage nibble tables for the whole block
    if (tid < jmax) {
        // st1pf[j]: bm[b, j, i0..i0+7]  (score/PV modulation types)
        const int* rowp = bmb + (size_t)tid * Tdim + i0;
        int4 lo = *(const int4*)rowp;
        int4 hi = *(const int4*)(rowp + 4);
        st1pf[tid] =
            ((unsigned)(lo.x & 15)) | (((unsigned)(lo.y & 15)) << 4) |
            (((unsigned)(lo.z & 15)) << 8) | (((unsigned)(lo.w & 15)) << 12) |
            (((unsigned)(hi.x & 15)) << 16) | (((unsigned)(hi.y & 15)) << 20) |
            (((unsigned)(hi.z & 15)) << 24) | (((unsigned)(hi.w & 15)) << 28);
        // st2pf[j]: bm[b, i0+ii, j]  (attn-bias types; coalesced across tid)
        unsigned w2 = 0;
#pragma unroll
        for (int iiq = 0; iiq < 8; ++iiq)
            w2 |= ((unsigned)(bmb[(size_t)(i0 + iiq) * Tdim + tid] & 15)) << (iiq * 4);
        st2pf[tid] = w2;
    }
    // build qm[ii][t] = fp16(q[i0+ii] * ekt[t]) directly from global
    for (int idx = tid; idx < TI * NTYPES * 8; idx += 512) {
        int eq = idx & 7;
        int t = (idx >> 3) & (NTYPES - 1);
        int r = idx >> 7;
        float4 qv = *(const float4*)&qbase[(size_t)(i0 + r) * Edim + eq * 4];
        float4 ev = *(const float4*)&ekt[t * Cdim + h * Edim + eq * 4];
        union { __half2 h[2]; uint2 u; } pk;
        pk.h[0] = __floats2half2_rn(qv.x * ev.x, qv.y * ev.y);
        pk.h[1] = __floats2half2_rn(qv.z * ev.z, qv.w * ev.w);
        *(uint2*)&qm[r][t][eq * 4] = pk.u;   // 8B store, 8B-aligned
    }
    __syncthreads();   // [bar 1] qm + tables ready

    // ---- Pass A: coalesced global k + prefetch rotation + fp16 dot;
    //      attn-bias added at score write (st2pf) ----
    {
        const int g = lane >> 2;     // j sub-index within wave's 16-row strip
        const int c = lane & 3;      // e-slice: elements c*8 .. c*8+7
        const int e0 = c << 3;
        int jb = wave << 4;
        if (jb <= imax) {
            const float* krow = kbase + ((size_t)(jb + g) << 5) + e0;
            float4 k0 = *(const float4*)(krow);
            float4 k1 = *(const float4*)(krow + 4);
            unsigned tp = st1pf[jb + g];
            unsigned tp2 = st2pf[jb + g];
            for (;;) {
                const int jbn = jb + 128;
                const bool more = (jbn <= imax);   // wave-uniform
                float4 kn0, kn1;
                unsigned tpn, tpn2;
                if (more) {                         // prefetch next strip
                    const float* krn = kbase + ((size_t)(jbn + g) << 5) + e0;
                    kn0 = *(const float4*)(krn);
                    kn1 = *(const float4*)(krn + 4);
                    tpn = st1pf[jbn + g];
                    tpn2 = st2pf[jbn + g];
                }
                const int j = jb + g;
                // convert k slice to packed fp16 once per strip
                __half2 kh0 = __floats2half2_rn(k0.x, k0.y);
                __half2 kh1 = __floats2half2_rn(k0.z, k0.w);
                __half2 kh2 = __floats2half2_rn(k1.x, k1.y);
                __half2 kh3 = __floats2half2_rn(k1.z, k1.w);
                float my0 = 0.f, my1 = 0.f;
#pragma unroll
                for (int ii = 0; ii < 8; ++ii) {
                    int t1 = (tp >> (ii * 4)) & 15;
                    uint4 qw = *(const uint4*)&qm[ii][t1][e0];  // 1x b128
                    __half2 q0 = *(__half2*)&qw.x;
                    __half2 q1 = *(__half2*)&qw.y;
                    __half2 q2 = *(__half2*)&qw.z;
                    __half2 q3 = *(__half2*)&qw.w;
                    __half2 sh = __hmul2(q0, kh0);
                    sh = __hfma2(q1, kh1, sh);
                    sh = __hfma2(q2, kh2, sh);
                    sh = __hfma2(q3, kh3, sh);
                    float s = __low2float(sh) + __high2float(sh);
                    s = quad_reduce_add(s);          // all 4 lanes hold full dot
                    if (ii < 4) my0 = (c == ii) ? s : my0;       // static select
                    else        my1 = (c == (ii - 4)) ? s : my1;
                }
                if (j <= i0 + c)
                    ss[c][j] = my0 * inv_scale + sabt[(tp2 >> (c * 4)) & 15];
                if (j <= i0 + c + 4)
                    ss[c + 4][j] = my1 * inv_scale + sabt[(tp2 >> ((c + 4) * 4)) & 15];
                if (!more) break;
                k0 = kn0; k1 = kn1; tp = tpn; tp2 = tpn2; jb = jbn;
            }
        }
    }
    __syncthreads();   // [bar 2] all (biased) scores written

    // Pass-B chunk-0 loads issued EARLY (hide under softmax + [bar 3]).
    const int gid8 = tid >> 3;       // 64 groups of 8 (8 lanes share a j)
    const int eqg4 = (tid & 7) << 2;
    float4 v4c = *(const float4*)&vbase[((size_t)gid8 << 5) + eqg4];
    unsigned tpc = st1pf[gid8];

    // --- softmax over active chunks: pure LDS max scan, then exp+sum.
    //     Bias already in ss (pass A) -> no global bm traffic here.
    {
        int ii = wave;
        int i = i0 + ii;
        const int cmax = i >> 6;                    // wave-uniform chunk bound
        float m = -1e30f;
        for (int c = 0; c <= cmax; ++c) {
            int j = (c << 6) + lane;
            float val = ss[ii][j];                  // garbage if j>i, masked next
            m = fmaxf(m, (j <= i) ? val : -1e30f);
        }
        for (int off = 32; off; off >>= 1) m = fmaxf(m, __shfl_xor(m, off));
        float sum = 0.f;
        for (int c = 0; c <= cmax; ++c) {
            int j = (c << 6) + lane;
            float p = __expf(ss[ii][j] - m);
            p = (j <= i) ? p : 0.f;                 // kill idle-lane exp
            sum += p;
            if (j <= i) ss[ii][j] = p;
        }
        for (int off = 32; off; off >>= 1) sum += __shfl_xor(sum, off);
        if (lane == 0) sinv[ii] = 1.0f / sum;
    }
    __syncthreads();   // [bar 3] probs + sinv visible

    // ---- Pass B: PV. Global-direct v + prefetch rotation, PACKED float2 ----
    v2f acc[TI][2];
#pragma unroll
    for (int ii = 0; ii < TI; ++ii) { acc[ii][0] = (v2f)0.f; acc[ii][1] = (v2f)0.f; }
    for (int jc = 0;; ++jc) {
        const bool more = ((jc + 1) << 6) <= imax;   // block-uniform
        float4 v4n;
        unsigned tpn;
        if (more) {                                   // prefetch next chunk
            const int jn = ((jc + 1) << 6) + gid8;
            v4n = *(const float4*)&vbase[((size_t)jn << 5) + eqg4];
            tpn = st1pf[jn];
        }
        const int j = (jc << 6) + gid8;
        const v2f v01 = {v4c.x, v4c.y};
        const v2f v23 = {v4c.z, v4c.w};
#pragma unroll
        for (int ii = 0; ii < TI; ++ii) {
            const int i = i0 + ii;
            if ((jc << 6) > i) continue;        // block-uniform skip
            float p = (j <= i) ? ss[ii][j] : 0.f;
            int t1 = (tpc >> (ii * 4)) & 15;
            const v2f e01 = *(const v2f*)&sevt[t1][eqg4];
            const v2f e23 = *(const v2f*)&sevt[t1][eqg4 + 2];
            v2f pp = {p, p};
            acc[ii][0] += (pp * e01) * v01;     // v_pk_mul + v_pk_fma
            acc[ii][1] += (pp * e23) * v23;
        }
        if (!more) break;
        v4c = v4n; tpc = tpn;
    }
    __syncthreads();   // [bar 4] all ss reads done -> spart may overlay
    // reduce across the wave's 8 groups (lane bits 3,4,5)
#pragma unroll
    for (int ii = 0; ii < TI; ++ii) {
#pragma unroll
        for (int m = 8; m <= 32; m <<= 1) {
            acc[ii][0][0] += __shfl_xor(acc[ii][0][0], m);
            acc[ii][0][1] += __shfl_xor(acc[ii][0][1], m);
            acc[ii][1][0] += __shfl_xor(acc[ii][1][0], m);
            acc[ii][1][1] += __shfl_xor(acc[ii][1][1], m);
        }
    }
    if (lane < 8) {
#pragma unroll
        for (int ii = 0; ii < TI; ++ii) {
            float4 av = make_float4(acc[ii][0][0], acc[ii][0][1],
                                    acc[ii][1][0], acc[ii][1][1]);
            *(float4*)&spart[((wave * TI + ii) << 5) + lane * 4] = av;
        }
    }
    __syncthreads();   // [bar 5]
    if (tid < TI * Edim) {
        int ii = tid >> 5, e = tid & 31;
        float yv = 0.f;
#pragma unroll
        for (int w = 0; w < 8; ++w) yv += spart[((w * TI + ii) << 5) + e];
        yv *= sinv[ii];
        y[((size_t)(b * Tdim + i0 + ii)) * Cdim + h * Edim + e] = yv;
    }
}

// ---------------------------------------------------------------------------
// Kernel 3: proj GEMM (M=1024, K=256, N=256) -> d_out (B,T,C).
// 32x32 tiles, 256 blocks.
// ---------------------------------------------------------------------------
__global__ __launch_bounds__(256) void proj_gemm_kernel(
    const float* __restrict__ A, const float* __restrict__ Bw,
    float* __restrict__ out)
{
    const int N = Cdim;
    const int K = Cdim;
    __shared__ float As[16][34];
    __shared__ float Bs[16][36];
    int m0 = blockIdx.y * 32;
    int n0 = blockIdx.x * 32;
    int tid = threadIdx.x;
    int tr = tid >> 3;          // 0..31 (row)
    int tc = tid & 7;           // 0..7  (col quad)
    float acc[4] = {};

    for (int k0 = 0; k0 < K; k0 += 16) {
        if (tid < 128) {
            int r = tid >> 2, kq = (tid & 3) * 4;
            float4 av = *(const float4*)(A + (size_t)(m0 + r) * K + k0 + kq);
            As[kq + 0][r] = av.x;
            As[kq + 1][r] = av.y;
            As[kq + 2][r] = av.z;
            As[kq + 3][r] = av.w;
        } else {
            int t2 = tid - 128;
            int r = t2 >> 3, c = (t2 & 7) * 4;   // 16 rows x 32 cols
            *(float4*)&Bs[r][c] =
                *(const float4*)(Bw + (size_t)(k0 + r) * N + n0 + c);
        }
        __syncthreads();
#pragma unroll
        for (int kk = 0; kk < 16; ++kk) {
            float a = As[kk][tr];
            float4 b4 = *(float4*)&Bs[kk][tc * 4];
            acc[0] = fmaf(a, b4.x, acc[0]);
            acc[1] = fmaf(a, b4.y, acc[1]);
            acc[2] = fmaf(a, b4.z, acc[2]);
            acc[3] = fmaf(a, b4.w, acc[3]);
        }
        __syncthreads();
    }
    float4 val = make_float4(acc[0], acc[1], acc[2], acc[3]);
    *(float4*)&out[(size_t)(m0 + tr) * N + n0 + tc * 4] = val;
}

// ---------------------------------------------------------------------------
extern "C" void kernel_launch(void* const* d_in, const int* in_sizes, int n_in,
                              void* d_out, int out_size, void* d_ws, size_t ws_size,
                              hipStream_t stream) {
    (void)in_sizes; (void)n_in; (void)out_size; (void)ws_size;
    const float* x = (const float*)d_in[0];
    const int* bias_matrix = (const int*)d_in[1];
    const float* w_attn = (const float*)d_in[2];
    const float* w_proj = (const float*)d_in[3];
    const float* w_edge_k = (const float*)d_in[4];
    const float* w_edge_v = (const float*)d_in[5];
    const float* edge_emb = (const float*)d_in[6];
    const float* attn_bias = (const float*)d_in[7];
    float* out = (float*)d_out;

    const size_t n_qkv = (size_t)Bdim * Hdim * Tdim * Edim;
    float* ws = (float*)d_ws;
    float* qT = ws;
    float* kT = qT + n_qkv;
    float* vT = kT + n_qkv;
    float* y = vT + n_qkv;
    float* ekt = y + (size_t)Bdim * Tdim * Cdim;
    float* evt = ekt + (size_t)NTYPES * Cdim;

    pre_kernel<<<400, 256, 0, stream>>>(x, w_attn, edge_emb, w_edge_k, w_edge_v,
                                        qT, kT, vT, ekt, evt);
    attn_kernel<<<dim3(64 * 16), 512, 0, stream>>>(qT, kT, vT, bias_matrix,
                                                   ekt, evt, attn_bias, y);
    proj_gemm_kernel<<<dim3(8, 32), 256, 0, stream>>>(y, w_proj, out);
}